// Round 3
// baseline (225.476 us; speedup 1.0000x reference)
//
#include <hip/hip_runtime.h>
#include <cmath>
#include <cstring>
#include <vector>
#include <algorithm>

// ---------------------------------------------------------------------------
// Host-side precompute: u = conj(A)·ones for Candan's DFrFT, N=128, a=0.5.
// Only the even-parity (C2) eigenvectors contribute (ones is even-symmetric).
// u[h] = sum_{m=0..64} i^m * q_m[h] * (sum_n q_m[n]),  q_m = m-th DESCENDING
// even eigenvector = P·[vc[:,64-m]; 0].
// Identity used by the GPU path: conj(A)·A = I (E orthonormal, |f|=1), so the
// channel mix commutes out and only the bias picks up the spectral pattern.
// ---------------------------------------------------------------------------

struct UV { float ur[128]; float ui[128]; };
static UV g_uv;

namespace {

constexpr int NN = 128;

void matmul_d(const std::vector<double>& A, const std::vector<double>& B,
              std::vector<double>& C, int n) {
  for (int i = 0; i < n; ++i)
    for (int j = 0; j < n; ++j) {
      double s = 0.0;
      for (int k = 0; k < n; ++k) s += A[(size_t)i*n+k] * B[(size_t)k*n+j];
      C[(size_t)i*n+j] = s;
    }
}

// Cyclic Jacobi eigensolver for symmetric A (row-major n x n, destroyed).
void jacobi_eigh(std::vector<double>& A, int n, std::vector<double>& V,
                 std::vector<double>& lam) {
  V.assign((size_t)n*n, 0.0);
  for (int i = 0; i < n; ++i) V[(size_t)i*n+i] = 1.0;
  for (int sweep = 0; sweep < 200; ++sweep) {
    double off = 0.0;
    for (int p = 0; p < n; ++p)
      for (int q = p+1; q < n; ++q) off += A[(size_t)p*n+q]*A[(size_t)p*n+q];
    if (off < 1e-24) break;
    for (int p = 0; p < n-1; ++p)
      for (int q = p+1; q < n; ++q) {
        double apq = A[(size_t)p*n+q];
        if (std::fabs(apq) < 1e-300) continue;
        double app = A[(size_t)p*n+p], aqq = A[(size_t)q*n+q];
        double tau = (aqq - app) / (2.0*apq);
        double t = (tau >= 0 ? 1.0 : -1.0) / (std::fabs(tau) + std::sqrt(1.0 + tau*tau));
        double c = 1.0/std::sqrt(1.0 + t*t), s = t*c;
        for (int k = 0; k < n; ++k) {
          double akp = A[(size_t)k*n+p], akq = A[(size_t)k*n+q];
          A[(size_t)k*n+p] = c*akp - s*akq;
          A[(size_t)k*n+q] = s*akp + c*akq;
        }
        for (int k = 0; k < n; ++k) {
          double apk = A[(size_t)p*n+k], aqk = A[(size_t)q*n+k];
          A[(size_t)p*n+k] = c*apk - s*aqk;
          A[(size_t)q*n+k] = s*apk + c*aqk;
        }
        for (int k = 0; k < n; ++k) {
          double vkp = V[(size_t)k*n+p], vkq = V[(size_t)k*n+q];
          V[(size_t)k*n+p] = c*vkp - s*vkq;
          V[(size_t)k*n+q] = s*vkp + c*vkq;
        }
      }
  }
  lam.resize(n);
  for (int i = 0; i < n; ++i) lam[i] = A[(size_t)i*n+i];
}

bool init_uv() {
  const int n = NN, r = NN/2;                 // N even: even=1, r=64
  const double c = 1.0/std::sqrt(2.0);
  const double PI = 3.14159265358979323846;
  std::vector<double> S((size_t)n*n, 0.0), P((size_t)n*n, 0.0);
  for (int i = 0; i < n; ++i) {
    S[(size_t)i*n+i] = 2.0*std::cos(2.0*PI*i/n);
    S[(size_t)i*n + (i+1)%n] += 1.0;
    S[(size_t)i*n + (i-1+n)%n] += 1.0;
  }
  P[0] = 1.0;
  for (int i = 1; i <= r-1; ++i) { P[(size_t)i*n+i] = c;  P[(size_t)i*n + (n-i)] = c; }
  P[(size_t)r*n+r] = 1.0;
  for (int i = r+1; i < n; ++i)  { P[(size_t)i*n+i] = -c; P[(size_t)i*n + (n-i)] = c; }
  std::vector<double> Pt((size_t)n*n), T((size_t)n*n), CS((size_t)n*n);
  for (int i = 0; i < n; ++i)
    for (int j = 0; j < n; ++j) Pt[(size_t)i*n+j] = P[(size_t)j*n+i];
  matmul_d(P, S, T, n);
  matmul_d(T, Pt, CS, n);
  const int m = r + 1;                        // 65x65 even block
  std::vector<double> C2((size_t)m*m);
  for (int i = 0; i < m; ++i)
    for (int j = 0; j < m; ++j) C2[(size_t)i*m+j] = CS[(size_t)i*n+j];
  std::vector<double> V, lam;
  jacobi_eigh(C2, m, V, lam);
  std::vector<int> idx(m);
  for (int i = 0; i < m; ++i) idx[i] = i;
  std::sort(idx.begin(), idx.end(), [&](int a, int b){ return lam[a] < lam[b]; });
  double ure[NN] = {0}, uim[NN] = {0};
  for (int mm = 0; mm < m; ++mm) {
    int col = idx[m-1-mm];                    // mm-th in DESCENDING order
    double q[NN];
    q[0] = V[(size_t)0*m+col];
    for (int j = 1; j <= r-1; ++j) q[j] = c * V[(size_t)j*m+col];
    q[r] = V[(size_t)r*m+col];
    for (int j = r+1; j < n; ++j)  q[j] = c * V[(size_t)(n-j)*m+col];
    double ssum = 0.0;
    for (int j = 0; j < n; ++j) ssum += q[j];
    switch (mm & 3) {                         // weight i^m
      case 0: for (int h = 0; h < n; ++h) ure[h] += q[h]*ssum; break;
      case 1: for (int h = 0; h < n; ++h) uim[h] += q[h]*ssum; break;
      case 2: for (int h = 0; h < n; ++h) ure[h] -= q[h]*ssum; break;
      case 3: for (int h = 0; h < n; ++h) uim[h] -= q[h]*ssum; break;
    }
  }
  for (int h = 0; h < n; ++h) { g_uv.ur[h] = (float)ure[h]; g_uv.ui[h] = (float)uim[h]; }
  return true;
}

bool g_inited = init_uv();

} // namespace

// ---------------------------------------------------------------------------
// GPU kernels
// ---------------------------------------------------------------------------

// Transpose 64x64 weights into d_ws so the main loop can read contiguous
// o-rows with wave-uniform scalar loads.
__global__ __launch_bounds__(256) void transpose_w_kernel(
    const float* __restrict__ wr, const float* __restrict__ wi,
    float* __restrict__ wTr, float* __restrict__ wTi) {
  int t = blockIdx.x * 256 + threadIdx.x;     // 4096 total
  if (t < 4096) {
    int o = t >> 6, i = t & 63;
    wTr[i*64 + o] = wr[t];
    wTi[i*64 + o] = wi[t];
  }
}

// LDS-free main kernel. Block = 512 threads (8 waves) = one (b, h-row).
// Wave w owns outputs [8w, 8w+8); each lane owns 2 adjacent positions.
// x rows are read directly from global (coalesced float2/lane); the 8 waves
// share each 512B row via L1. No barriers; depth-2 prefetch pipelines loads
// against the FMA stream. VGPR target <=64 for 8 waves/SIMD occupancy.
__global__ __launch_bounds__(512, 8) void spec_main_kernel(
    const float* __restrict__ x,
    const float* __restrict__ wTr, const float* __restrict__ wTi,
    const float* __restrict__ br, const float* __restrict__ bi,
    float* __restrict__ out, UV uv) {
  const int tid  = threadIdx.x;
  const int bid  = blockIdx.x;
  const int b    = bid >> 7;
  const int hrow = bid & 127;
  const int lane = tid & 63;
  const int o0   = __builtin_amdgcn_readfirstlane((tid >> 6) << 3);
  const int w0   = lane << 1;                 // two adjacent positions per lane
  const long long pos0 = (long long)hrow << 7;
  const float* xp = x + ((long long)b << 20) + pos0 + w0;  // +i*16384 per chan

  // Rank-1 bias init: bias[o,h,w] = bc[o]*u[h]*u[w]
  const float uhr = uv.ur[hrow], uhi = uv.ui[hrow];
  const float v0r = uv.ur[w0],   v0i = uv.ui[w0];
  const float v1r = uv.ur[w0+1], v1i = uv.ui[w0+1];
  const float g0r = uhr*v0r - uhi*v0i, g0i = uhr*v0i + uhi*v0r;
  const float g1r = uhr*v1r - uhi*v1i, g1i = uhr*v1i + uhi*v1r;

  float accr[8][2], acci[8][2];
#pragma unroll
  for (int oo = 0; oo < 8; ++oo) {
    float bro = br[o0+oo], bio = bi[o0+oo];
    accr[oo][0] = bro*g0r - bio*g0i;  acci[oo][0] = bro*g0i + bio*g0r;
    accr[oo][1] = bro*g1r - bio*g1i;  acci[oo][1] = bro*g1i + bio*g1r;
  }

  // Main loop: y[o,p] += sum_i w[o,i] * x[i,p]. Weights via uniform scalar
  // loads (SGPR operand in v_fmac); x via per-lane global float2 with
  // depth-2 prefetch (no LDS, no barrier).
  float2 c0 = *(const float2*)(xp);
  float2 c1 = *(const float2*)(xp + 16384);
#pragma unroll 1
  for (int i = 0; i < 64; i += 2) {
    const int p0 = (i + 2 < 64) ? i + 2 : 63;
    const int p1 = (i + 3 < 64) ? i + 3 : 63;
    float2 n0 = *(const float2*)(xp + ((long long)p0 << 14));
    float2 n1 = *(const float2*)(xp + ((long long)p1 << 14));
    const float* wr0 = wTr + (i << 6) + o0;
    const float* wi0 = wTi + (i << 6) + o0;
#pragma unroll
    for (int oo = 0; oo < 8; ++oo) {
      float wr = wr0[oo], wi = wi0[oo];
      accr[oo][0] += wr*c0.x;  accr[oo][1] += wr*c0.y;
      acci[oo][0] += wi*c0.x;  acci[oo][1] += wi*c0.y;
    }
#pragma unroll
    for (int oo = 0; oo < 8; ++oo) {
      float wr = wr0[64+oo], wi = wi0[64+oo];
      accr[oo][0] += wr*c1.x;  accr[oo][1] += wr*c1.y;
      acci[oo][0] += wi*c1.x;  acci[oo][1] += wi*c1.y;
    }
    c0 = n0; c1 = n1;
  }

  // Store: out[(part*16 + b)*64 + o][pos], float2 per (o, part).
  long long baseR = (((long long)(b*64 + o0)) << 14) + pos0 + w0;
  long long baseI = baseR + ((long long)(16*64) << 14);
#pragma unroll
  for (int oo = 0; oo < 8; ++oo) {
    *(float2*)&out[baseR + ((long long)oo << 14)] = make_float2(accr[oo][0], accr[oo][1]);
    *(float2*)&out[baseI + ((long long)oo << 14)] = make_float2(acci[oo][0], acci[oo][1]);
  }
}

extern "C" void kernel_launch(void* const* d_in, const int* in_sizes, int n_in,
                              void* d_out, int out_size, void* d_ws, size_t ws_size,
                              hipStream_t stream) {
  (void)in_sizes; (void)n_in; (void)out_size; (void)ws_size; (void)g_inited;
  const float* x  = (const float*)d_in[0];
  const float* wr = (const float*)d_in[1];
  const float* wi = (const float*)d_in[2];
  const float* br = (const float*)d_in[3];
  const float* bi = (const float*)d_in[4];
  float* out = (float*)d_out;
  float* wTr = (float*)d_ws;                  // 16 KB
  float* wTi = wTr + 4096;                    // 16 KB

  transpose_w_kernel<<<16, 256, 0, stream>>>(wr, wi, wTr, wTi);
  spec_main_kernel<<<2048, 512, 0, stream>>>(x, wTr, wTi, br, bi, out, g_uv);
}

// Round 5
// 209.567 us; speedup vs baseline: 1.0759x; 1.0759x over previous
//
#include <hip/hip_runtime.h>
#include <cmath>
#include <cstring>
#include <vector>
#include <algorithm>

// ---------------------------------------------------------------------------
// Host-side precompute: u = conj(A)·ones for Candan's DFrFT, N=128, a=0.5.
// Only the even-parity (C2) eigenvectors contribute (ones is even-symmetric).
// u[h] = sum_{m=0..64} i^m * q_m[h] * (sum_n q_m[n]),  q_m = m-th DESCENDING
// even eigenvector = P·[vc[:,64-m]; 0].
// Identity used by the GPU path: conj(A)·A = I (E orthonormal, |f|=1), so the
// channel mix commutes out and only the bias picks up the spectral pattern.
// ---------------------------------------------------------------------------

struct UV { float ur[128]; float ui[128]; };
static UV g_uv;

namespace {

constexpr int NN = 128;

void matmul_d(const std::vector<double>& A, const std::vector<double>& B,
              std::vector<double>& C, int n) {
  for (int i = 0; i < n; ++i)
    for (int j = 0; j < n; ++j) {
      double s = 0.0;
      for (int k = 0; k < n; ++k) s += A[(size_t)i*n+k] * B[(size_t)k*n+j];
      C[(size_t)i*n+j] = s;
    }
}

// Cyclic Jacobi eigensolver for symmetric A (row-major n x n, destroyed).
void jacobi_eigh(std::vector<double>& A, int n, std::vector<double>& V,
                 std::vector<double>& lam) {
  V.assign((size_t)n*n, 0.0);
  for (int i = 0; i < n; ++i) V[(size_t)i*n+i] = 1.0;
  for (int sweep = 0; sweep < 200; ++sweep) {
    double off = 0.0;
    for (int p = 0; p < n; ++p)
      for (int q = p+1; q < n; ++q) off += A[(size_t)p*n+q]*A[(size_t)p*n+q];
    if (off < 1e-24) break;
    for (int p = 0; p < n-1; ++p)
      for (int q = p+1; q < n; ++q) {
        double apq = A[(size_t)p*n+q];
        if (std::fabs(apq) < 1e-300) continue;
        double app = A[(size_t)p*n+p], aqq = A[(size_t)q*n+q];
        double tau = (aqq - app) / (2.0*apq);
        double t = (tau >= 0 ? 1.0 : -1.0) / (std::fabs(tau) + std::sqrt(1.0 + tau*tau));
        double c = 1.0/std::sqrt(1.0 + t*t), s = t*c;
        for (int k = 0; k < n; ++k) {
          double akp = A[(size_t)k*n+p], akq = A[(size_t)k*n+q];
          A[(size_t)k*n+p] = c*akp - s*akq;
          A[(size_t)k*n+q] = s*akp + c*akq;
        }
        for (int k = 0; k < n; ++k) {
          double apk = A[(size_t)p*n+k], aqk = A[(size_t)q*n+k];
          A[(size_t)p*n+k] = c*apk - s*aqk;
          A[(size_t)q*n+k] = s*apk + c*aqk;
        }
        for (int k = 0; k < n; ++k) {
          double vkp = V[(size_t)k*n+p], vkq = V[(size_t)k*n+q];
          V[(size_t)k*n+p] = c*vkp - s*vkq;
          V[(size_t)k*n+q] = s*vkp + c*vkq;
        }
      }
  }
  lam.resize(n);
  for (int i = 0; i < n; ++i) lam[i] = A[(size_t)i*n+i];
}

bool init_uv() {
  const int n = NN, r = NN/2;                 // N even: even=1, r=64
  const double c = 1.0/std::sqrt(2.0);
  const double PI = 3.14159265358979323846;
  std::vector<double> S((size_t)n*n, 0.0), P((size_t)n*n, 0.0);
  for (int i = 0; i < n; ++i) {
    S[(size_t)i*n+i] = 2.0*std::cos(2.0*PI*i/n);
    S[(size_t)i*n + (i+1)%n] += 1.0;
    S[(size_t)i*n + (i-1+n)%n] += 1.0;
  }
  P[0] = 1.0;
  for (int i = 1; i <= r-1; ++i) { P[(size_t)i*n+i] = c;  P[(size_t)i*n + (n-i)] = c; }
  P[(size_t)r*n+r] = 1.0;
  for (int i = r+1; i < n; ++i)  { P[(size_t)i*n+i] = -c; P[(size_t)i*n + (n-i)] = c; }
  std::vector<double> Pt((size_t)n*n), T((size_t)n*n), CS((size_t)n*n);
  for (int i = 0; i < n; ++i)
    for (int j = 0; j < n; ++j) Pt[(size_t)i*n+j] = P[(size_t)j*n+i];
  matmul_d(P, S, T, n);
  matmul_d(T, Pt, CS, n);
  const int m = r + 1;                        // 65x65 even block
  std::vector<double> C2((size_t)m*m);
  for (int i = 0; i < m; ++i)
    for (int j = 0; j < m; ++j) C2[(size_t)i*m+j] = CS[(size_t)i*n+j];
  std::vector<double> V, lam;
  jacobi_eigh(C2, m, V, lam);
  std::vector<int> idx(m);
  for (int i = 0; i < m; ++i) idx[i] = i;
  std::sort(idx.begin(), idx.end(), [&](int a, int b){ return lam[a] < lam[b]; });
  double ure[NN] = {0}, uim[NN] = {0};
  for (int mm = 0; mm < m; ++mm) {
    int col = idx[m-1-mm];                    // mm-th in DESCENDING order
    double q[NN];
    q[0] = V[(size_t)0*m+col];
    for (int j = 1; j <= r-1; ++j) q[j] = c * V[(size_t)j*m+col];
    q[r] = V[(size_t)r*m+col];
    for (int j = r+1; j < n; ++j)  q[j] = c * V[(size_t)(n-j)*m+col];
    double ssum = 0.0;
    for (int j = 0; j < n; ++j) ssum += q[j];
    switch (mm & 3) {                         // weight i^m
      case 0: for (int h = 0; h < n; ++h) ure[h] += q[h]*ssum; break;
      case 1: for (int h = 0; h < n; ++h) uim[h] += q[h]*ssum; break;
      case 2: for (int h = 0; h < n; ++h) ure[h] -= q[h]*ssum; break;
      case 3: for (int h = 0; h < n; ++h) uim[h] -= q[h]*ssum; break;
    }
  }
  for (int h = 0; h < n; ++h) { g_uv.ur[h] = (float)ure[h]; g_uv.ui[h] = (float)uim[h]; }
  return true;
}

bool g_inited = init_uv();

} // namespace

// ---------------------------------------------------------------------------
// GPU kernels
// ---------------------------------------------------------------------------

typedef const float __attribute__((address_space(1)))* gas_fp;
typedef float __attribute__((address_space(3)))* las_fp;

// Transpose 64x64 weights into d_ws so the main loop can read contiguous
// o-rows with wave-uniform scalar loads.
__global__ __launch_bounds__(256) void transpose_w_kernel(
    const float* __restrict__ wr, const float* __restrict__ wi,
    float* __restrict__ wTr, float* __restrict__ wTi) {
  int t = blockIdx.x * 256 + threadIdx.x;     // 4096 total
  if (t < 4096) {
    int o = t >> 6, i = t & 63;
    wTr[i*64 + o] = wr[t];
    wTi[i*64 + o] = wi[t];
  }
}

// Block = 512 threads (8 waves) = one (b, h-row-pair): 2 rows x 128 pos.
// Wave w owns outputs [8w, 8w+8); lane owns 4 adjacent positions in one row
// (row = lane>>5, pos = (lane&31)*4). x is staged to LDS in two async halves
// via global_load_lds width-16 (half1 flies under half0's compute).
// acc = 8 o x 4 pos x 2 parts = 64 VGPR; ~100 total -> 4 waves/SIMD cap;
// LDS 64KB -> 2 blocks/CU.
__global__ __launch_bounds__(512, 4) void spec_main_kernel(
    const float* __restrict__ x,
    const float* __restrict__ wTr, const float* __restrict__ wTi,
    const float* __restrict__ br, const float* __restrict__ bi,
    float* __restrict__ out, UV uv) {
  __shared__ float xs[64][256];               // 64 KB: [chan][row*128+pos]
  const int tid  = threadIdx.x;
  const int bid  = blockIdx.x;
  const int b    = bid >> 6;
  const int pair = bid & 63;
  const int wave = tid >> 6;                  // 0..7
  const int lane = tid & 63;
  const int row  = lane >> 5;                 // 0..1 (per-lane!)
  const int p4   = (lane & 31) << 2;          // 0,4,...,124
  const int o0   = __builtin_amdgcn_readfirstlane(wave << 3);
  const int hrow = (pair << 1) + row;
  const int loff = (row << 7) + p4;           // LDS offset within a channel

  // Per-lane global address for staging/compute: x[b, c, hrow, p4..p4+3]
  const float* xb = x + ((long long)b << 20) + ((long long)hrow << 7) + p4;

  // Stage half0 (channels 0..31): wave w issues channels 4w..4w+3.
  // HW semantics: LDS dest = wave-uniform base + lane*16; lane l lands at
  // xs[c][4l] == xs[c][(l>>5)*128 + (l&31)*4] which matches the global addr.
#pragma unroll
  for (int j = 0; j < 4; ++j) {
    int c = (wave << 2) + j;
    __builtin_amdgcn_global_load_lds((gas_fp)(xb + ((long long)c << 14)),
                                     (las_fp)&xs[c][0], 16, 0, 0);
  }
  __syncthreads();                            // implicit vmcnt(0): half0 ready

  // Stage half1 (channels 32..63) asynchronously under half0's compute.
#pragma unroll
  for (int j = 0; j < 4; ++j) {
    int c = 32 + (wave << 2) + j;
    __builtin_amdgcn_global_load_lds((gas_fp)(xb + ((long long)c << 14)),
                                     (las_fp)&xs[c][0], 16, 0, 0);
  }

  // Rank-1 bias: bias[o,h,w] = bc[o]*u[h]*u[w]
  const float uhr = uv.ur[hrow], uhi = uv.ui[hrow];
  float gr[4], gi[4];
#pragma unroll
  for (int k = 0; k < 4; ++k) {
    float vr = uv.ur[p4+k], vi = uv.ui[p4+k];
    gr[k] = uhr*vr - uhi*vi;
    gi[k] = uhr*vi + uhi*vr;
  }

  float accr[8][4], acci[8][4];
#pragma unroll
  for (int oo = 0; oo < 8; ++oo) {
    float bro = br[o0+oo], bio = bi[o0+oo];
#pragma unroll
    for (int k = 0; k < 4; ++k) {
      accr[oo][k] = bro*gr[k] - bio*gi[k];
      acci[oo][k] = bro*gi[k] + bio*gr[k];
    }
  }

  // Compute half0: per channel 1 ds_read_b128 + 64 FMAs; weights via
  // wave-uniform s_loads.
#pragma unroll 4
  for (int i = 0; i < 32; ++i) {
    float4 xv = *(const float4*)&xs[i][loff];
    const float* wr0 = wTr + (i << 6) + o0;
    const float* wi0 = wTi + (i << 6) + o0;
#pragma unroll
    for (int oo = 0; oo < 8; ++oo) {
      float wr = wr0[oo], wi = wi0[oo];
      accr[oo][0] += wr*xv.x;  accr[oo][1] += wr*xv.y;
      accr[oo][2] += wr*xv.z;  accr[oo][3] += wr*xv.w;
      acci[oo][0] += wi*xv.x;  acci[oo][1] += wi*xv.y;
      acci[oo][2] += wi*xv.z;  acci[oo][3] += wi*xv.w;
    }
  }
  __syncthreads();                            // implicit vmcnt(0): half1 ready

#pragma unroll 4
  for (int i = 32; i < 64; ++i) {
    float4 xv = *(const float4*)&xs[i][loff];
    const float* wr0 = wTr + (i << 6) + o0;
    const float* wi0 = wTi + (i << 6) + o0;
#pragma unroll
    for (int oo = 0; oo < 8; ++oo) {
      float wr = wr0[oo], wi = wi0[oo];
      accr[oo][0] += wr*xv.x;  accr[oo][1] += wr*xv.y;
      accr[oo][2] += wr*xv.z;  accr[oo][3] += wr*xv.w;
      acci[oo][0] += wi*xv.x;  acci[oo][1] += wi*xv.y;
      acci[oo][2] += wi*xv.z;  acci[oo][3] += wi*xv.w;
    }
  }

  // Store: out[part][b][o][h][w], float4 per (o, part).
  const long long posg  = ((long long)hrow << 7) + p4;
  long long baseR = ((long long)(b*64 + o0) << 14) + posg;
  long long baseI = baseR + ((long long)(16*64) << 14);
#pragma unroll
  for (int oo = 0; oo < 8; ++oo) {
    *(float4*)&out[baseR + ((long long)oo << 14)] =
        make_float4(accr[oo][0], accr[oo][1], accr[oo][2], accr[oo][3]);
    *(float4*)&out[baseI + ((long long)oo << 14)] =
        make_float4(acci[oo][0], acci[oo][1], acci[oo][2], acci[oo][3]);
  }
}

extern "C" void kernel_launch(void* const* d_in, const int* in_sizes, int n_in,
                              void* d_out, int out_size, void* d_ws, size_t ws_size,
                              hipStream_t stream) {
  (void)in_sizes; (void)n_in; (void)out_size; (void)ws_size; (void)g_inited;
  const float* x  = (const float*)d_in[0];
  const float* wr = (const float*)d_in[1];
  const float* wi = (const float*)d_in[2];
  const float* br = (const float*)d_in[3];
  const float* bi = (const float*)d_in[4];
  float* out = (float*)d_out;
  float* wTr = (float*)d_ws;                  // 16 KB
  float* wTi = wTr + 4096;                    // 16 KB

  transpose_w_kernel<<<16, 256, 0, stream>>>(wr, wi, wTr, wTi);
  spec_main_kernel<<<1024, 512, 0, stream>>>(x, wTr, wTi, br, bi, out, g_uv);
}

// Round 6
// 194.048 us; speedup vs baseline: 1.1620x; 1.0800x over previous
//
#include <hip/hip_runtime.h>
#include <cmath>
#include <cstring>
#include <vector>
#include <algorithm>

// ---------------------------------------------------------------------------
// Host-side precompute: u = conj(A)·ones for Candan's DFrFT, N=128, a=0.5.
// Only the even-parity (C2) eigenvectors contribute (ones is even-symmetric).
// Identity used by the GPU path: conj(A)·A = I (E orthonormal, |f|=1), so the
// channel mix commutes out and only the bias picks up the spectral pattern.
// ---------------------------------------------------------------------------

struct UV { float ur[128]; float ui[128]; };
static UV g_uv;

namespace {

constexpr int NN = 128;

void matmul_d(const std::vector<double>& A, const std::vector<double>& B,
              std::vector<double>& C, int n) {
  for (int i = 0; i < n; ++i)
    for (int j = 0; j < n; ++j) {
      double s = 0.0;
      for (int k = 0; k < n; ++k) s += A[(size_t)i*n+k] * B[(size_t)k*n+j];
      C[(size_t)i*n+j] = s;
    }
}

void jacobi_eigh(std::vector<double>& A, int n, std::vector<double>& V,
                 std::vector<double>& lam) {
  V.assign((size_t)n*n, 0.0);
  for (int i = 0; i < n; ++i) V[(size_t)i*n+i] = 1.0;
  for (int sweep = 0; sweep < 200; ++sweep) {
    double off = 0.0;
    for (int p = 0; p < n; ++p)
      for (int q = p+1; q < n; ++q) off += A[(size_t)p*n+q]*A[(size_t)p*n+q];
    if (off < 1e-24) break;
    for (int p = 0; p < n-1; ++p)
      for (int q = p+1; q < n; ++q) {
        double apq = A[(size_t)p*n+q];
        if (std::fabs(apq) < 1e-300) continue;
        double app = A[(size_t)p*n+p], aqq = A[(size_t)q*n+q];
        double tau = (aqq - app) / (2.0*apq);
        double t = (tau >= 0 ? 1.0 : -1.0) / (std::fabs(tau) + std::sqrt(1.0 + tau*tau));
        double c = 1.0/std::sqrt(1.0 + t*t), s = t*c;
        for (int k = 0; k < n; ++k) {
          double akp = A[(size_t)k*n+p], akq = A[(size_t)k*n+q];
          A[(size_t)k*n+p] = c*akp - s*akq;
          A[(size_t)k*n+q] = s*akp + c*akq;
        }
        for (int k = 0; k < n; ++k) {
          double apk = A[(size_t)p*n+k], aqk = A[(size_t)q*n+k];
          A[(size_t)p*n+k] = c*apk - s*aqk;
          A[(size_t)q*n+k] = s*apk + c*aqk;
        }
        for (int k = 0; k < n; ++k) {
          double vkp = V[(size_t)k*n+p], vkq = V[(size_t)k*n+q];
          V[(size_t)k*n+p] = c*vkp - s*vkq;
          V[(size_t)k*n+q] = s*vkp + c*vkq;
        }
      }
  }
  lam.resize(n);
  for (int i = 0; i < n; ++i) lam[i] = A[(size_t)i*n+i];
}

bool init_uv() {
  const int n = NN, r = NN/2;                 // N even: even=1, r=64
  const double c = 1.0/std::sqrt(2.0);
  const double PI = 3.14159265358979323846;
  std::vector<double> S((size_t)n*n, 0.0), P((size_t)n*n, 0.0);
  for (int i = 0; i < n; ++i) {
    S[(size_t)i*n+i] = 2.0*std::cos(2.0*PI*i/n);
    S[(size_t)i*n + (i+1)%n] += 1.0;
    S[(size_t)i*n + (i-1+n)%n] += 1.0;
  }
  P[0] = 1.0;
  for (int i = 1; i <= r-1; ++i) { P[(size_t)i*n+i] = c;  P[(size_t)i*n + (n-i)] = c; }
  P[(size_t)r*n+r] = 1.0;
  for (int i = r+1; i < n; ++i)  { P[(size_t)i*n+i] = -c; P[(size_t)i*n + (n-i)] = c; }
  std::vector<double> Pt((size_t)n*n), T((size_t)n*n), CS((size_t)n*n);
  for (int i = 0; i < n; ++i)
    for (int j = 0; j < n; ++j) Pt[(size_t)i*n+j] = P[(size_t)j*n+i];
  matmul_d(P, S, T, n);
  matmul_d(T, Pt, CS, n);
  const int m = r + 1;                        // 65x65 even block
  std::vector<double> C2((size_t)m*m);
  for (int i = 0; i < m; ++i)
    for (int j = 0; j < m; ++j) C2[(size_t)i*m+j] = CS[(size_t)i*n+j];
  std::vector<double> V, lam;
  jacobi_eigh(C2, m, V, lam);
  std::vector<int> idx(m);
  for (int i = 0; i < m; ++i) idx[i] = i;
  std::sort(idx.begin(), idx.end(), [&](int a, int b){ return lam[a] < lam[b]; });
  double ure[NN] = {0}, uim[NN] = {0};
  for (int mm = 0; mm < m; ++mm) {
    int col = idx[m-1-mm];                    // mm-th in DESCENDING order
    double q[NN];
    q[0] = V[(size_t)0*m+col];
    for (int j = 1; j <= r-1; ++j) q[j] = c * V[(size_t)j*m+col];
    q[r] = V[(size_t)r*m+col];
    for (int j = r+1; j < n; ++j)  q[j] = c * V[(size_t)(n-j)*m+col];
    double ssum = 0.0;
    for (int j = 0; j < n; ++j) ssum += q[j];
    switch (mm & 3) {                         // weight i^m
      case 0: for (int h = 0; h < n; ++h) ure[h] += q[h]*ssum; break;
      case 1: for (int h = 0; h < n; ++h) uim[h] += q[h]*ssum; break;
      case 2: for (int h = 0; h < n; ++h) ure[h] -= q[h]*ssum; break;
      case 3: for (int h = 0; h < n; ++h) uim[h] -= q[h]*ssum; break;
    }
  }
  for (int h = 0; h < n; ++h) { g_uv.ur[h] = (float)ure[h]; g_uv.ui[h] = (float)uim[h]; }
  return true;
}

bool g_inited = init_uv();

} // namespace

// ---------------------------------------------------------------------------
// GPU kernels
// ---------------------------------------------------------------------------

typedef const float __attribute__((address_space(1)))* gas_fp;
typedef float __attribute__((address_space(3)))* las_fp;
typedef __bf16 bf16x8 __attribute__((ext_vector_type(8)));
typedef float f32x16 __attribute__((ext_vector_type(16)));
union FW { uint4 u; bf16x8 v; };

// Pre-pack per-lane MFMA fragments into d_ws:
//  fragW[1024] uint4 : A-operand w fragments. Entry ((kk*2+ot)*2+p)*64+lane,
//    element j = bf16(w_p[o=ot*32+(lane&31)][k=kk*16+(lane>>5)*4+(j&3)+8*(j>>2)])
//    (same intra-lane k-map as the B-frag builder, so any bijective mis-guess
//     of the HW k-slot assignment cancels in the MFMA dot product).
//  fragB[2048] float2: bias bc[o] in the 32x32 C/D layout (m74/m101-verified):
//    entry (ot*16+r)*64+lane -> o = ot*32+(r&3)+8*(r>>2)+4*(lane>>5).
__global__ __launch_bounds__(256) void prep_kernel(
    const float* __restrict__ wr, const float* __restrict__ wi,
    const float* __restrict__ br, const float* __restrict__ bi,
    uint4* __restrict__ fragW, float2* __restrict__ fragB) {
  int t = blockIdx.x * 256 + threadIdx.x;     // 3072 total
  if (t < 1024) {
    int lane = t & 63, rest = t >> 6;         // rest = kk*4 + ot*2 + p
    int p = rest & 1, ot = (rest >> 1) & 1, kk = rest >> 2;
    const float* w = p ? wi : wr;
    int o  = ot*32 + (lane & 31);
    int kh = (lane >> 5) << 2;
    unsigned short us[8];
#pragma unroll
    for (int j = 0; j < 8; ++j) {
      int cch = kk*16 + kh + (j & 3) + ((j >> 2) << 3);
      union { __bf16 h; unsigned short s; } cv;
      cv.h = (__bf16)w[o*64 + cch];
      us[j] = cv.s;
    }
    uint4 u;
    u.x = (unsigned)us[0] | ((unsigned)us[1] << 16);
    u.y = (unsigned)us[2] | ((unsigned)us[3] << 16);
    u.z = (unsigned)us[4] | ((unsigned)us[5] << 16);
    u.w = (unsigned)us[6] | ((unsigned)us[7] << 16);
    fragW[t] = u;
  } else if (t < 3072) {
    int q = t - 1024;
    int lane = q & 63, rr = q >> 6;           // rr = ot*16 + r
    int r = rr & 15, ot = rr >> 4;
    int o = ot*32 + (r & 3) + ((r >> 2) << 3) + ((lane >> 5) << 2);
    fragB[q] = make_float2(br[o], bi[o]);
  }
}

// Block = 512 threads (8 waves) = one (b, h-row-pair): 2 rows x 128 = 256 pos.
// Wave wv owns pos-strip [wv*32, wv*32+32). Per wave: 4 accumulators
// (o-tile 0/1 x real/imag), K-loop = 4 steps of mfma_f32_32x32x16_bf16.
// x staged fp32 to LDS in two async halves via global_load_lds (proven R5
// structure); B-fragments built from LDS with on-the-fly bf16 conversion.
__global__ __launch_bounds__(512, 4) void spec_main_kernel(
    const float* __restrict__ x,
    const uint4* __restrict__ fragW, const float2* __restrict__ fragB,
    float* __restrict__ out, UV uv) {
  __shared__ float xs[64][256];               // 64 KB: [chan][row*128+w]
  const int tid  = threadIdx.x;
  const int bid  = blockIdx.x;
  const int b    = bid >> 6;
  const int pair = bid & 63;
  const int wv   = tid >> 6;                  // 0..7
  const int lane = tid & 63;
  const int hl   = lane >> 5;                 // lane half
  const int p4   = (lane & 31) << 2;

  // Staging source: lane l of wave covers x[b, c, pair*2 + (l>>5), (l&31)*4+..]
  // -> LDS xs[c][l*16B] = xs[c][(l>>5)*128 + (l&31)*4]  (linear dest rule).
  const float* xb = x + ((long long)b << 20)
                      + ((long long)((pair << 1) + hl) << 7) + p4;

#pragma unroll
  for (int j = 0; j < 4; ++j) {
    int c = (wv << 2) + j;
    __builtin_amdgcn_global_load_lds((gas_fp)(xb + ((long long)c << 14)),
                                     (las_fp)&xs[c][0], 16, 0, 0);
  }
  __syncthreads();                            // half0 (ch 0..31) ready
#pragma unroll
  for (int j = 0; j < 4; ++j) {
    int c = 32 + (wv << 2) + j;
    __builtin_amdgcn_global_load_lds((gas_fp)(xb + ((long long)c << 14)),
                                     (las_fp)&xs[c][0], 16, 0, 0);
  }

  const int p = (wv << 5) + (lane & 31);      // pos in block tile [0,256)

  f32x16 zero;
#pragma unroll
  for (int i = 0; i < 16; ++i) zero[i] = 0.0f;
  f32x16 aR0 = zero, aI0 = zero, aR1 = zero, aI1 = zero;

  auto kstep = [&](int kk) {
    bf16x8 bv;                                // B-frag: x[k][p], same k-map as A
#pragma unroll
    for (int j = 0; j < 8; ++j) {
      int cch = kk*16 + (hl << 2) + (j & 3) + ((j >> 2) << 3);
      bv[j] = (__bf16)xs[cch][p];
    }
    const int base = (kk << 8);               // kk*4 entries * 64 lanes
    FW a0, a1, a2, a3;
    a0.u = fragW[base       + lane];          // ot0 real
    a1.u = fragW[base +  64 + lane];          // ot0 imag
    a2.u = fragW[base + 128 + lane];          // ot1 real
    a3.u = fragW[base + 192 + lane];          // ot1 imag
    aR0 = __builtin_amdgcn_mfma_f32_32x32x16_bf16(a0.v, bv, aR0, 0, 0, 0);
    aI0 = __builtin_amdgcn_mfma_f32_32x32x16_bf16(a1.v, bv, aI0, 0, 0, 0);
    aR1 = __builtin_amdgcn_mfma_f32_32x32x16_bf16(a2.v, bv, aR1, 0, 0, 0);
    aI1 = __builtin_amdgcn_mfma_f32_32x32x16_bf16(a3.v, bv, aI1, 0, 0, 0);
  };

  kstep(0); kstep(1);                         // channels 0..31
  __syncthreads();                            // half1 (ch 32..63) ready
  kstep(2); kstep(3);                         // channels 32..63

  // Epilogue: rank-1 bias add + store. C/D layout (verified m74/m101):
  // col(pos) = lane&31, row(o) = (r&3)+8*(r>>2)+4*(lane>>5).
  const int wcol = p & 127;
  const int h    = (pair << 1) + (p >> 7);
  const float uhr = uv.ur[h],    uhi = uv.ui[h];
  const float vr  = uv.ur[wcol], vi  = uv.ui[wcol];
  const float gr = uhr*vr - uhi*vi, gi = uhr*vi + uhi*vr;

  const long long base = ((long long)(b * 64) << 14) + ((long long)pair << 8) + p;
#pragma unroll
  for (int r = 0; r < 16; ++r) {
    float2 bc = fragB[(r << 6) + lane];
    int o = (r & 3) + ((r >> 2) << 3) + (hl << 2);
    long long off = base + ((long long)o << 14);
    out[off]             = aR0[r] + bc.x*gr - bc.y*gi;
    out[off + (1 << 24)] = aI0[r] + bc.x*gi + bc.y*gr;
  }
#pragma unroll
  for (int r = 0; r < 16; ++r) {
    float2 bc = fragB[((16 + r) << 6) + lane];
    int o = 32 + (r & 3) + ((r >> 2) << 3) + (hl << 2);
    long long off = base + ((long long)o << 14);
    out[off]             = aR1[r] + bc.x*gr - bc.y*gi;
    out[off + (1 << 24)] = aI1[r] + bc.x*gi + bc.y*gr;
  }
}

extern "C" void kernel_launch(void* const* d_in, const int* in_sizes, int n_in,
                              void* d_out, int out_size, void* d_ws, size_t ws_size,
                              hipStream_t stream) {
  (void)in_sizes; (void)n_in; (void)out_size; (void)ws_size; (void)g_inited;
  const float* x  = (const float*)d_in[0];
  const float* wr = (const float*)d_in[1];
  const float* wi = (const float*)d_in[2];
  const float* br = (const float*)d_in[3];
  const float* bi = (const float*)d_in[4];
  float* out = (float*)d_out;
  uint4*  fragW = (uint4*)d_ws;                       // 16 KB
  float2* fragB = (float2*)((char*)d_ws + 16384);     // 16 KB

  prep_kernel<<<12, 256, 0, stream>>>(wr, wi, br, bi, fragW, fragB);
  spec_main_kernel<<<1024, 512, 0, stream>>>(x, fragW, fragB, out, g_uv);
}

// Round 8
// 190.604 us; speedup vs baseline: 1.1830x; 1.0181x over previous
//
#include <hip/hip_runtime.h>
#include <cmath>
#include <cstring>
#include <vector>
#include <algorithm>

// ---------------------------------------------------------------------------
// Host-side precompute: u = conj(A)·ones for Candan's DFrFT, N=128, a=0.5.
// Only the even-parity (C2) eigenvectors contribute (ones is even-symmetric).
// Identity used by the GPU path: conj(A)·A = I (E orthonormal, |f|=1), so the
// channel mix commutes out and only the bias picks up the spectral pattern.
// ---------------------------------------------------------------------------

struct UV { float ur[128]; float ui[128]; };
static UV g_uv;

namespace {

constexpr int NN = 128;

void matmul_d(const std::vector<double>& A, const std::vector<double>& B,
              std::vector<double>& C, int n) {
  for (int i = 0; i < n; ++i)
    for (int j = 0; j < n; ++j) {
      double s = 0.0;
      for (int k = 0; k < n; ++k) s += A[(size_t)i*n+k] * B[(size_t)k*n+j];
      C[(size_t)i*n+j] = s;
    }
}

void jacobi_eigh(std::vector<double>& A, int n, std::vector<double>& V,
                 std::vector<double>& lam) {
  V.assign((size_t)n*n, 0.0);
  for (int i = 0; i < n; ++i) V[(size_t)i*n+i] = 1.0;
  for (int sweep = 0; sweep < 200; ++sweep) {
    double off = 0.0;
    for (int p = 0; p < n; ++p)
      for (int q = p+1; q < n; ++q) off += A[(size_t)p*n+q]*A[(size_t)p*n+q];
    if (off < 1e-24) break;
    for (int p = 0; p < n-1; ++p)
      for (int q = p+1; q < n; ++q) {
        double apq = A[(size_t)p*n+q];
        if (std::fabs(apq) < 1e-300) continue;
        double app = A[(size_t)p*n+p], aqq = A[(size_t)q*n+q];
        double tau = (aqq - app) / (2.0*apq);
        double t = (tau >= 0 ? 1.0 : -1.0) / (std::fabs(tau) + std::sqrt(1.0 + tau*tau));
        double c = 1.0/std::sqrt(1.0 + t*t), s = t*c;
        for (int k = 0; k < n; ++k) {
          double akp = A[(size_t)k*n+p], akq = A[(size_t)k*n+q];
          A[(size_t)k*n+p] = c*akp - s*akq;
          A[(size_t)k*n+q] = s*akp + c*akq;
        }
        for (int k = 0; k < n; ++k) {
          double apk = A[(size_t)p*n+k], aqk = A[(size_t)q*n+k];
          A[(size_t)p*n+k] = c*apk - s*aqk;
          A[(size_t)q*n+k] = s*apk + c*aqk;
        }
        for (int k = 0; k < n; ++k) {
          double vkp = V[(size_t)k*n+p], vkq = V[(size_t)k*n+q];
          V[(size_t)k*n+p] = c*vkp - s*vkq;
          V[(size_t)k*n+q] = s*vkp + c*vkq;
        }
      }
  }
  lam.resize(n);
  for (int i = 0; i < n; ++i) lam[i] = A[(size_t)i*n+i];
}

bool init_uv() {
  const int n = NN, r = NN/2;                 // N even: even=1, r=64
  const double c = 1.0/std::sqrt(2.0);
  const double PI = 3.14159265358979323846;
  std::vector<double> S((size_t)n*n, 0.0), P((size_t)n*n, 0.0);
  for (int i = 0; i < n; ++i) {
    S[(size_t)i*n+i] = 2.0*std::cos(2.0*PI*i/n);
    S[(size_t)i*n + (i+1)%n] += 1.0;
    S[(size_t)i*n + (i-1+n)%n] += 1.0;
  }
  P[0] = 1.0;
  for (int i = 1; i <= r-1; ++i) { P[(size_t)i*n+i] = c;  P[(size_t)i*n + (n-i)] = c; }
  P[(size_t)r*n+r] = 1.0;
  for (int i = r+1; i < n; ++i)  { P[(size_t)i*n+i] = -c; P[(size_t)i*n + (n-i)] = c; }
  std::vector<double> Pt((size_t)n*n), T((size_t)n*n), CS((size_t)n*n);
  for (int i = 0; i < n; ++i)
    for (int j = 0; j < n; ++j) Pt[(size_t)i*n+j] = P[(size_t)j*n+i];
  matmul_d(P, S, T, n);
  matmul_d(T, Pt, CS, n);
  const int m = r + 1;                        // 65x65 even block
  std::vector<double> C2((size_t)m*m);
  for (int i = 0; i < m; ++i)
    for (int j = 0; j < m; ++j) C2[(size_t)i*m+j] = CS[(size_t)i*n+j];
  std::vector<double> V, lam;
  jacobi_eigh(C2, m, V, lam);
  std::vector<int> idx(m);
  for (int i = 0; i < m; ++i) idx[i] = i;
  std::sort(idx.begin(), idx.end(), [&](int a, int b){ return lam[a] < lam[b]; });
  double ure[NN] = {0}, uim[NN] = {0};
  for (int mm = 0; mm < m; ++mm) {
    int col = idx[m-1-mm];                    // mm-th in DESCENDING order
    double q[NN];
    q[0] = V[(size_t)0*m+col];
    for (int j = 1; j <= r-1; ++j) q[j] = c * V[(size_t)j*m+col];
    q[r] = V[(size_t)r*m+col];
    for (int j = r+1; j < n; ++j)  q[j] = c * V[(size_t)(n-j)*m+col];
    double ssum = 0.0;
    for (int j = 0; j < n; ++j) ssum += q[j];
    switch (mm & 3) {                         // weight i^m
      case 0: for (int h = 0; h < n; ++h) ure[h] += q[h]*ssum; break;
      case 1: for (int h = 0; h < n; ++h) uim[h] += q[h]*ssum; break;
      case 2: for (int h = 0; h < n; ++h) ure[h] -= q[h]*ssum; break;
      case 3: for (int h = 0; h < n; ++h) uim[h] -= q[h]*ssum; break;
    }
  }
  for (int h = 0; h < n; ++h) { g_uv.ur[h] = (float)ure[h]; g_uv.ui[h] = (float)uim[h]; }
  return true;
}

bool g_inited = init_uv();

} // namespace

// ---------------------------------------------------------------------------
// GPU kernels
// ---------------------------------------------------------------------------

typedef const float __attribute__((address_space(1)))* gas_fp;
typedef float __attribute__((address_space(3)))* las_fp;
typedef __bf16 bf16x8 __attribute__((ext_vector_type(8)));
typedef float f32x16 __attribute__((ext_vector_type(16)));
union FW { uint4 u; bf16x8 v; };

// Pre-pack per-lane MFMA fragments into d_ws (layout as in R6, verified):
//  fragW[1024] uint4 : A-operand w fragments, entry ((kk*2+ot)*2+p)*64+lane,
//    element j = bf16(w_p[o=ot*32+(lane&31)][k=kk*16+(lane>>5)*4+(j&3)+8*(j>>2)])
//    (A and B share the same intra-lane k-map, so any bijective mis-guess of
//     the HW k-slot assignment cancels in the MFMA dot product).
//  fragB[2048] float2: bias bc[o] in the 32x32 C/D layout (m74/m101-verified):
//    entry (ot*16+r)*64+lane -> o = ot*32+(r&3)+8*(r>>2)+4*(lane>>5).
__global__ __launch_bounds__(256) void prep_kernel(
    const float* __restrict__ wr, const float* __restrict__ wi,
    const float* __restrict__ br, const float* __restrict__ bi,
    uint4* __restrict__ fragW, float2* __restrict__ fragB) {
  int t = blockIdx.x * 256 + threadIdx.x;     // 3072 total
  if (t < 1024) {
    int lane = t & 63, rest = t >> 6;         // rest = kk*4 + ot*2 + p
    int p = rest & 1, ot = (rest >> 1) & 1, kk = rest >> 2;
    const float* w = p ? wi : wr;
    int o  = ot*32 + (lane & 31);
    int kh = (lane >> 5) << 2;
    unsigned short us[8];
#pragma unroll
    for (int j = 0; j < 8; ++j) {
      int cch = kk*16 + kh + (j & 3) + ((j >> 2) << 3);
      union { __bf16 h; unsigned short s; } cv;
      cv.h = (__bf16)w[o*64 + cch];
      us[j] = cv.s;
    }
    uint4 u;
    u.x = (unsigned)us[0] | ((unsigned)us[1] << 16);
    u.y = (unsigned)us[2] | ((unsigned)us[3] << 16);
    u.z = (unsigned)us[4] | ((unsigned)us[5] << 16);
    u.w = (unsigned)us[6] | ((unsigned)us[7] << 16);
    fragW[t] = u;
  } else if (t < 3072) {
    int q = t - 1024;
    int lane = q & 63, rr = q >> 6;           // rr = ot*16 + r
    int r = rr & 15, ot = rr >> 4;
    int o = ot*32 + (r & 3) + ((r >> 2) << 3) + ((lane >> 5) << 2);
    fragB[q] = make_float2(br[o], bi[o]);
  }
}

// Block = 256 threads (4 waves) = ONE (b, hrow): 64 ch x 128 pos = 32 KB LDS
// -> 4 blocks/CU, ONE barrier per block. Wave wv owns pos-strip
// [wv*32, wv*32+32); 4 K-steps of mfma_f32_32x32x16_bf16 x {2 o-tiles, R/I}.
__global__ __launch_bounds__(256, 4) void spec_main_kernel(
    const float* __restrict__ x,
    const uint4* __restrict__ fragW, const float2* __restrict__ fragB,
    float* __restrict__ out, UV uv) {
  __shared__ float xs[64][128];               // 32 KB: [chan][pos]
  const int tid  = threadIdx.x;
  const int bid  = blockIdx.x;                // 2048 = b*128 + hrow
  const int b    = bid >> 7;
  const int hrow = bid & 127;
  const int wv   = tid >> 6;                  // 0..3
  const int lane = tid & 63;
  const int hl   = lane >> 5;                 // lane half

  // Stage all 64 channels: one gll_dwordx4 covers 2 channel-rows (1 KB).
  // Lane l -> global x[b, c0+(l>>5), hrow, (l&31)*4]; LDS dest linear
  // &xs[c0][0] + 16*l lands lane l at xs[c0+(l>>5)][(l&31)*4]. Match.
  const float* xb = x + ((long long)b << 20) + ((long long)hrow << 7)
                      + ((long long)hl << 14) + ((lane & 31) << 2);
#pragma unroll
  for (int j = 0; j < 8; ++j) {
    int c0 = (wv << 4) + (j << 1);
    __builtin_amdgcn_global_load_lds((gas_fp)(xb + ((long long)c0 << 14)),
                                     (las_fp)&xs[c0][0], 16, 0, 0);
  }
  __syncthreads();                            // implicit vmcnt(0): tile ready

  const int p = (wv << 5) + (lane & 31);      // pos in row [0,128)

  f32x16 zero;
#pragma unroll
  for (int i = 0; i < 16; ++i) zero[i] = 0.0f;
  f32x16 aR0 = zero, aI0 = zero, aR1 = zero, aI1 = zero;

  auto kstep = [&](int kk) {
    bf16x8 bv;                                // B-frag: x[k][p], same k-map as A
#pragma unroll
    for (int j = 0; j < 8; ++j) {
      int cch = kk*16 + (hl << 2) + (j & 3) + ((j >> 2) << 3);
      bv[j] = (__bf16)xs[cch][p];
    }
    const int base = (kk << 8);               // kk*4 entries * 64 lanes
    FW a0, a1, a2, a3;
    a0.u = fragW[base       + lane];          // ot0 real
    a1.u = fragW[base +  64 + lane];          // ot0 imag
    a2.u = fragW[base + 128 + lane];          // ot1 real
    a3.u = fragW[base + 192 + lane];          // ot1 imag
    aR0 = __builtin_amdgcn_mfma_f32_32x32x16_bf16(a0.v, bv, aR0, 0, 0, 0);
    aI0 = __builtin_amdgcn_mfma_f32_32x32x16_bf16(a1.v, bv, aI0, 0, 0, 0);
    aR1 = __builtin_amdgcn_mfma_f32_32x32x16_bf16(a2.v, bv, aR1, 0, 0, 0);
    aI1 = __builtin_amdgcn_mfma_f32_32x32x16_bf16(a3.v, bv, aI1, 0, 0, 0);
  };

  kstep(0); kstep(1); kstep(2); kstep(3);     // all 64 channels

  // Epilogue: rank-1 bias add + store. C/D layout (verified m74/m101):
  // col(pos) = lane&31, row(o) = (r&3)+8*(r>>2)+4*(lane>>5).
  const float uhr = uv.ur[hrow], uhi = uv.ui[hrow];
  const float vr  = uv.ur[p],    vi  = uv.ui[p];
  const float gr = uhr*vr - uhi*vi, gi = uhr*vi + uhi*vr;

  const long long base = ((long long)(b * 64) << 14) + ((long long)hrow << 7) + p;
#pragma unroll
  for (int r = 0; r < 16; ++r) {
    float2 bc = fragB[(r << 6) + lane];
    int o = (r & 3) + ((r >> 2) << 3) + (hl << 2);
    long long off = base + ((long long)o << 14);
    out[off]             = aR0[r] + bc.x*gr - bc.y*gi;
    out[off + (1 << 24)] = aI0[r] + bc.x*gi + bc.y*gr;
  }
#pragma unroll
  for (int r = 0; r < 16; ++r) {
    float2 bc = fragB[((16 + r) << 6) + lane];
    int o = 32 + (r & 3) + ((r >> 2) << 3) + (hl << 2);
    long long off = base + ((long long)o << 14);
    out[off]             = aR1[r] + bc.x*gr - bc.y*gi;
    out[off + (1 << 24)] = aI1[r] + bc.x*gi + bc.y*gr;
  }
}

extern "C" void kernel_launch(void* const* d_in, const int* in_sizes, int n_in,
                              void* d_out, int out_size, void* d_ws, size_t ws_size,
                              hipStream_t stream) {
  (void)in_sizes; (void)n_in; (void)out_size; (void)ws_size; (void)g_inited;
  const float* x  = (const float*)d_in[0];
  const float* wr = (const float*)d_in[1];
  const float* wi = (const float*)d_in[2];
  const float* br = (const float*)d_in[3];
  const float* bi = (const float*)d_in[4];
  float* out = (float*)d_out;
  uint4*  fragW = (uint4*)d_ws;                       // 16 KB
  float2* fragB = (float2*)((char*)d_ws + 16384);     // 16 KB

  prep_kernel<<<12, 256, 0, stream>>>(wr, wi, br, bi, fragW, fragB);
  spec_main_kernel<<<2048, 256, 0, stream>>>(x, fragW, fragB, out, g_uv);
}